// Round 8
// baseline (5269.765 us; speedup 1.0000x reference)
//
#include <hip/hip_runtime.h>

// DISCO block: conv(11x11, disk support) -> InstanceNorm -> LeakyReLU, twice.
// B=4, C=32, H=W=256. fp32 (no fp32 MFMA on CDNA4 -> VALU conv).
//
// R7 (from R6 @ 657us/conv, VALUBusy 54%, Occ 46%):
//  - occupancy 4->8 waves/SIMD: thread = 1px x 16oc, og=tid>>8 wave-uniform;
//    16x16 tile x 2 og, 1024 blocks = 4/CU x 8 waves = 32 waves/CU.
//    (R6's 1 thread/px decomposition capped the chip at 16 waves/CU.)
//  - per-(ci,row) pixel prefetch into rv[11] (static idx, literal disk test)
//    -> one lgkmcnt region per row, not per tap (s_load/ds_read share lgkmcnt)
//  - weights kern[ic][og][tap][16] -> s_load_dwordx8/tap, 5.7KB/(ci,og) slab

#define HALO 5
#define TSX  16            // output tile x
#define TSY  16            // output tile y
#define TW   26            // TSX + 2*HALO
#define LDSY 26            // TSY + 2*HALO
#define TWP  27            // padded LDS row stride (odd)
#define ICC  8             // input channels per LDS chunk (8*26*27*4B = 22.5 KB)

// ---------------------------------------------------------------------------
// Kernel-builder: PSI basis (fp64, matches numpy) -> dense kernels in layout
// kern[ic][og][tap][16]  (og = oc>>4).
// ---------------------------------------------------------------------------
__global__ void build_kern_kernel(const float* __restrict__ w1,
                                  const float* __restrict__ w2,
                                  float* __restrict__ kern1,
                                  float* __restrict__ kern2) {
  __shared__ float psi[36 * 121];
  const int blk   = blockIdx.x;   // 0..63
  const int layer = blk >> 5;
  const int i     = blk & 31;
  const int tid   = threadIdx.x;  // 128 threads
  const double PI     = 3.141592653589793;
  const double TWO_PI = 6.283185307179586;
  for (int t = tid; t < 121; t += 128) {
    const int ky = t / 11, kx = t % 11;
    const double y = (ky - 5) / 255.0;
    const double x = (kx - 5) / 255.0;
    const double r = sqrt(x * x + y * y);
    double phi = atan2(y, x);
    if (phi < 0.0) phi += TWO_PI;
    const double inside = (r <= 0.02) ? 1.0 : 0.0;
    const double dr   = 0.02 / 5.0;
    const double dphi = TWO_PI / 7.0;
    psi[t] = (float)(fmax(0.0, 1.0 - r / dr) * inside);
    for (int j = 1; j < 6; ++j) {
      const double rad = fmax(0.0, 1.0 - fabs(r - j * dr) / dr) * inside;
      for (int k = 0; k < 7; ++k) {
        double d = fmod(phi - k * dphi + PI, TWO_PI);
        if (d < 0.0) d += TWO_PI;
        d = fabs(d - PI);
        const double ang = fmax(0.0, 1.0 - d / dphi);
        psi[(1 + (j - 1) * 7 + k) * 121 + t] = (float)(rad * ang);
      }
    }
  }
  __syncthreads();
  const float* w  = layer ? w2 : w1;
  float*       ko = layer ? kern2 : kern1;
  for (int idx = tid; idx < 121 * 32; idx += 128) {
    const int t = idx >> 5;
    const int o = idx & 31;
    const float* wp = w + (o * 32 + i) * 36;  // w[o][i][k], K=36
    float s = 0.f;
#pragma unroll
    for (int k = 0; k < 36; ++k) s = fmaf(wp[k], psi[k * 121 + t], s);
    // layout: [ic=i][og=o>>4][tap=t][j=o&15]
    ko[((size_t)(i * 2 + (o >> 4)) * 121 + t) * 16 + (o & 15)] = s;
  }
}

// ---------------------------------------------------------------------------
// Direct conv. Block: 16x16 px, 2 oc-groups, one batch. 512 threads:
//   x = tid&15, y = (tid>>4)&15, og = tid>>8 (wave-uniform).
// Thread = 1 px x 16 oc (acc[16]). Pixel tile in LDS; per-(ci,row) pixels
// prefetched to rv[11] (static idx); weights via uniform s_load_dwordx8.
// ---------------------------------------------------------------------------
template <bool NORM_IN>
__global__ __launch_bounds__(512, 8)
void conv_kernel(const float* __restrict__ in, const float* __restrict__ kern,
                 float* __restrict__ out, const float2* __restrict__ stats) {
  __shared__ float tile[ICC][LDSY * TWP];  // 8*26*27*4B = 22.5 KB
  const int tid = threadIdx.x;
  const int x   = tid & 15;
  const int y   = (tid >> 4) & 15;
  const int og  = tid >> 8;          // 0..1, wave-uniform
  const int bx0 = blockIdx.x * TSX;
  const int by0 = blockIdx.y * TSY;
  const int b   = blockIdx.z;

  float acc[16];
#pragma unroll
  for (int j = 0; j < 16; ++j) acc[j] = 0.f;

  for (int ic0 = 0; ic0 < 32; ic0 += ICC) {
    __syncthreads();
    // ---- stage ICC channels of the haloed tile ----
    for (int idx = tid; idx < ICC * LDSY * TW; idx += 512) {
      const int ci  = idx / (LDSY * TW);
      const int rem = idx - ci * (LDSY * TW);
      const int yy  = rem / TW;
      const int xx  = rem - yy * TW;
      const int gy  = by0 + yy - HALO;
      const int gx  = bx0 + xx - HALO;
      float v = 0.f;
      if ((unsigned)gy < 256u && (unsigned)gx < 256u) {
        v = in[(((b << 5) + ic0 + ci) << 16) + (gy << 8) + gx];
        if (NORM_IN) {
          const float2 st = stats[(b << 5) + ic0 + ci];
          v = (v - st.x) * st.y;
          v = v < 0.f ? 0.2f * v : v;
        }
      }
      tile[ci][yy * TWP + xx] = v;
    }
    __syncthreads();
    // ---- accumulate ----
    for (int ci = 0; ci < ICC; ++ci) {
      const float* tb = &tile[ci][y * TWP + x];
      // weights for (ic, og): contiguous [tap][16]
      const float* kb = kern + (size_t)((ic0 + ci) * 2 + og) * (121 * 16);
#pragma unroll
      for (int kdy = 0; kdy < 11; ++kdy) {
        // row prefetch: all disk taps of this row -> registers (static idx)
        float rv[11];
#pragma unroll
        for (int kdx = 0; kdx < 11; ++kdx) {
          if ((kdy - 5) * (kdy - 5) + (kdx - 5) * (kdx - 5) > 26) continue;
          rv[kdx] = tb[kdy * TWP + kdx];
        }
#pragma unroll
        for (int kdx = 0; kdx < 11; ++kdx) {
          if ((kdy - 5) * (kdy - 5) + (kdx - 5) * (kdx - 5) > 26)
            continue;  // outside disk: kern==0 (folds at compile time)
          const float* wp = kb + (kdy * 11 + kdx) * 16;  // s_load_dwordx8 x2
#pragma unroll
          for (int o = 0; o < 16; ++o)
            acc[o] = fmaf(wp[o], rv[kdx], acc[o]);
        }
      }
    }
  }
  // ---- write raw (pre-norm) conv output: 16 oc, 1 px per thread ----
  const int gy = by0 + y;
  const int gx = bx0 + x;
#pragma unroll
  for (int k = 0; k < 16; ++k) {
    const int o = og * 16 + k;
    out[(((b << 5) + o) << 16) + (gy << 8) + gx] = acc[k];
  }
}

// ---------------------------------------------------------------------------
// Per-(b,c) plane mean / rstd. One block per plane, no atomics.
// ---------------------------------------------------------------------------
__global__ void stats_kernel(const float* __restrict__ y,
                             float2* __restrict__ stats) {
  const int bo  = blockIdx.x;            // 0..127
  const int tid = threadIdx.x;           // 256 threads
  const float4* p = reinterpret_cast<const float4*>(y + (size_t)bo * 65536);
  float s = 0.f, q = 0.f;
  for (int i = tid; i < 16384; i += 256) {
    const float4 v = p[i];
    s += v.x + v.y + v.z + v.w;
    q += v.x * v.x + v.y * v.y + v.z * v.z + v.w * v.w;
  }
#pragma unroll
  for (int off = 32; off > 0; off >>= 1) {
    s += __shfl_down(s, off);
    q += __shfl_down(q, off);
  }
  __shared__ float sh[8];
  const int lane = tid & 63, wid = tid >> 6;
  if (lane == 0) { sh[wid] = s; sh[4 + wid] = q; }
  __syncthreads();
  if (tid == 0) {
    const float S = sh[0] + sh[1] + sh[2] + sh[3];
    const float Q = sh[4] + sh[5] + sh[6] + sh[7];
    const float mean = S * (1.f / 65536.f);
    const float var  = Q * (1.f / 65536.f) - mean * mean;
    stats[bo] = make_float2(mean, __frsqrt_rn(var + 1e-5f));
  }
}

// ---------------------------------------------------------------------------
// Final in-place InstanceNorm + LeakyReLU on d_out.
// ---------------------------------------------------------------------------
__global__ void finalize_kernel(float* __restrict__ y,
                                const float2* __restrict__ stats) {
  const int n4 = (4 * 32 * 65536) / 4;  // 2097152 float4s
  float4* p = reinterpret_cast<float4*>(y);
  for (int i = blockIdx.x * blockDim.x + threadIdx.x; i < n4;
       i += gridDim.x * blockDim.x) {
    float4 v = p[i];
    const float2 st = stats[i >> 14];   // 16384 float4 per plane
    float t;
    t = (v.x - st.x) * st.y; v.x = t < 0.f ? 0.2f * t : t;
    t = (v.y - st.x) * st.y; v.y = t < 0.f ? 0.2f * t : t;
    t = (v.z - st.x) * st.y; v.z = t < 0.f ? 0.2f * t : t;
    t = (v.w - st.x) * st.y; v.w = t < 0.f ? 0.2f * t : t;
    p[i] = v;
  }
}

// ---------------------------------------------------------------------------
extern "C" void kernel_launch(void* const* d_in, const int* in_sizes, int n_in,
                              void* d_out, int out_size, void* d_ws,
                              size_t ws_size, hipStream_t stream) {
  const float* image = (const float*)d_in[0];
  const float* w1    = (const float*)d_in[1];
  const float* w2    = (const float*)d_in[2];
  float* out = (float*)d_out;
  float* ws  = (float*)d_ws;

  // ws layout (floats): kern1[123904] kern2[123904] y1[8388608] stats[512]
  float*  kern1  = ws;
  float*  kern2  = ws + 123904;
  float*  y1     = ws + 247808;
  float2* stats1 = (float2*)(ws + 247808 + 8388608);
  float2* stats2 = stats1 + 128;

  build_kern_kernel<<<64, 128, 0, stream>>>(w1, w2, kern1, kern2);

  dim3 cgrid(16, 16, 4);  // 16x16 tiles x 2 og, batch; 1024 blocks = 4/CU
  conv_kernel<false><<<cgrid, 512, 0, stream>>>(image, kern1, y1, nullptr);
  stats_kernel<<<128, 256, 0, stream>>>(y1, stats1);
  conv_kernel<true><<<cgrid, 512, 0, stream>>>(y1, kern2, out, stats1);
  stats_kernel<<<128, 256, 0, stream>>>(out, stats2);
  finalize_kernel<<<2048, 256, 0, stream>>>(out, stats2);
}

// Round 9
// 383.118 us; speedup vs baseline: 13.7550x; 13.7550x over previous
//
#include <hip/hip_runtime.h>

// DISCO block via bf16-split MFMA implicit GEMM (R8).
// C[oc][px] = sum_{ic,tap} W[oc][ic,tap] P[ic,tap][px], K-step = 32 = 4 taps x 8 ic,
// mfma_f32_16x16x32_bf16, hi/lo split (3 terms) for fp32-grade accuracy.
// Pixels: LDS [y][x][8ic] bf16 hi/lo (one b128/frag). Weights: pre-packed
// lane-ordered 1KB blocks in global (L2-resident), 16B/lane coalesced reads.

typedef __attribute__((ext_vector_type(8))) short short8;
typedef __attribute__((ext_vector_type(4))) float f32x4;

#define NT      92     // 89 disk taps + 3 zero pads (multiple of 4)
#define NSTEP   23     // K-steps per ic-chunk = NT*8/32
#define PSTR    27     // LDS px row stride (26 used + 1 pad)

__device__ inline ushort f2bf(float v) {                 // RNE fp32->bf16
  uint u = __builtin_bit_cast(uint, v);
  return (ushort)((u + 0x7fffu + ((u >> 16) & 1u)) >> 16);
}
__device__ inline float bf2f(ushort h) {
  uint u = ((uint)h) << 16;
  return __builtin_bit_cast(float, u);
}

// ---------------------------------------------------------------------------
// Builder: PSI basis (fp64, matches numpy) -> dense tap weights -> hi/lo
// bf16 packed per (chunk c, kstep s, split p, ochalf h): 1KB lane-ordered
// block; lane l=(q<<4)|(oc&15) holds W[oc=16h+(l&15)][tap=4s+q][ic=8c+j].
// ---------------------------------------------------------------------------
__global__ void build_kern_kernel(const float* __restrict__ w1,
                                  const float* __restrict__ w2,
                                  ushort* __restrict__ k1,
                                  ushort* __restrict__ k2) {
  __shared__ float psi[36 * 121];
  __shared__ int tpix[NT];
  const int blk   = blockIdx.x;   // 0..63
  const int layer = blk >> 5;
  const int i     = blk & 31;     // input channel
  const int tid   = threadIdx.x;  // 128 threads
  const double PI     = 3.141592653589793;
  const double TWO_PI = 6.283185307179586;
  for (int t = tid; t < 121; t += 128) {
    const int ky = t / 11, kx = t % 11;
    const double y = (ky - 5) / 255.0;
    const double x = (kx - 5) / 255.0;
    const double r = sqrt(x * x + y * y);
    double phi = atan2(y, x);
    if (phi < 0.0) phi += TWO_PI;
    const double inside = (r <= 0.02) ? 1.0 : 0.0;
    const double dr   = 0.02 / 5.0;
    const double dphi = TWO_PI / 7.0;
    psi[t] = (float)(fmax(0.0, 1.0 - r / dr) * inside);
    for (int j = 1; j < 6; ++j) {
      const double rad = fmax(0.0, 1.0 - fabs(r - j * dr) / dr) * inside;
      for (int k = 0; k < 7; ++k) {
        double d = fmod(phi - k * dphi + PI, TWO_PI);
        if (d < 0.0) d += TWO_PI;
        d = fabs(d - PI);
        const double ang = fmax(0.0, 1.0 - d / dphi);
        psi[(1 + (j - 1) * 7 + k) * 121 + t] = (float)(rad * ang);
      }
    }
  }
  if (tid == 0) {
    int c = 0;
    for (int kdy = 0; kdy < 11; ++kdy)
      for (int kdx = 0; kdx < 11; ++kdx)
        if ((kdy - 5) * (kdy - 5) + (kdx - 5) * (kdx - 5) <= 26)
          tpix[c++] = kdy * 11 + kdx;
    for (; c < NT; ++c) tpix[c] = -1;   // zero-pad taps
  }
  __syncthreads();
  const float* w  = layer ? w2 : w1;
  ushort*      ko = layer ? k2 : k1;
  const int cch = i >> 3, j = i & 7;
  for (int idx = tid; idx < NT * 32; idx += 128) {
    const int t = idx >> 5;
    const int o = idx & 31;
    float s = 0.f;
    const int tp = tpix[t];
    if (tp >= 0) {
      const float* wp = w + (o * 32 + i) * 36;   // w[o][i][k], K=36
#pragma unroll
      for (int k = 0; k < 36; ++k) s = fmaf(wp[k], psi[k * 121 + tp], s);
    }
    const ushort hi = f2bf(s);
    const ushort lo = f2bf(s - bf2f(hi));
    const int sk = t >> 2, q = t & 3, h = o >> 4;
    const int lane = (q << 4) | (o & 15);
    const size_t b0 = ((size_t)((cch * NSTEP + sk) * 2 + 0) * 2 + h) * 512 +
                      lane * 8 + j;
    const size_t b1 = ((size_t)((cch * NSTEP + sk) * 2 + 1) * 2 + h) * 512 +
                      lane * 8 + j;
    ko[b0] = hi;
    ko[b1] = lo;
  }
}

// ---------------------------------------------------------------------------
// MFMA conv. Block: 16x16 px, 32 oc, one batch; 256 thr = 4 waves, wave =
// 4 px-rows x 32 oc (8 C-tiles of 16x16x32). Per k-step: 4 global A-frags
// (Wh/Wl x ochalf), 8 LDS B-frags (Ph/Pl x 4 rows), 24 MFMAs.
// ---------------------------------------------------------------------------
template <bool NORM_IN>
__global__ __launch_bounds__(256, 4)
void conv_mfma_kernel(const float* __restrict__ in,
                      const ushort* __restrict__ wpack,
                      float* __restrict__ out,
                      const float2* __restrict__ stats) {
  __shared__ __align__(16) ushort ph[26 * PSTR * 8];
  __shared__ __align__(16) ushort pl[26 * PSTR * 8];
  __shared__ int toffs[NT];
  const int tid = threadIdx.x;
  const int l   = tid & 63;
  const int wv  = tid >> 6;        // wave 0..3
  const int x   = l & 15;
  const int q   = l >> 4;
  const int bx0 = blockIdx.x * 16;
  const int by0 = blockIdx.y * 16;
  const int b   = blockIdx.z;

  if (tid == 0) {
    int c = 0;
    for (int kdy = 0; kdy < 11; ++kdy)
      for (int kdx = 0; kdx < 11; ++kdx)
        if ((kdy - 5) * (kdy - 5) + (kdx - 5) * (kdx - 5) <= 26)
          toffs[c++] = ((kdy - 5) * PSTR + (kdx - 5)) * 16;
    for (; c < NT; ++c) toffs[c] = 0;
  }

  f32x4 acc[2][4];
#pragma unroll
  for (int h = 0; h < 2; ++h)
#pragma unroll
    for (int g = 0; g < 4; ++g) {
      acc[h][g][0] = 0.f; acc[h][g][1] = 0.f;
      acc[h][g][2] = 0.f; acc[h][g][3] = 0.f;
    }

  int rowb[4];
#pragma unroll
  for (int g = 0; g < 4; ++g)
    rowb[g] = (((4 * wv + g + 5) * PSTR + 5) + x) * 16;  // byte offset

  for (int c = 0; c < 4; ++c) {
    __syncthreads();
    // ---- stage 8 channels: fp32 -> hi/lo bf16, layout [y][x][ic] ----
    for (int idx = tid; idx < 8 * 26 * 26; idx += 256) {
      const int ci  = idx / 676;
      const int rem = idx - ci * 676;
      const int yy  = rem / 26;
      const int xx  = rem - yy * 26;
      const int gy  = by0 + yy - 5;
      const int gx  = bx0 + xx - 5;
      float v = 0.f;
      if ((unsigned)gy < 256u && (unsigned)gx < 256u) {
        v = in[(((b << 5) + (c << 3) + ci) << 16) + (gy << 8) + gx];
        if (NORM_IN) {
          const float2 st = stats[(b << 5) + (c << 3) + ci];
          v = (v - st.x) * st.y;
          v = v < 0.f ? 0.2f * v : v;
        }
      }
      const ushort hi = f2bf(v);
      const ushort lo = f2bf(v - bf2f(hi));
      ph[(yy * PSTR + xx) * 8 + ci] = hi;
      pl[(yy * PSTR + xx) * 8 + ci] = lo;
    }
    __syncthreads();
    // ---- K-loop: 23 k-steps of K=32 (4 taps x 8 ic) ----
    const ushort* wc = wpack + (size_t)c * (NSTEP * 4 * 512);
    for (int s = 0; s < NSTEP; ++s) {
      const int toff = toffs[s * 4 + q];
      const ushort* wb = wc + s * 2048;
      const short8 Ah0 = *reinterpret_cast<const short8*>(wb + 0 * 512 + l * 8);
      const short8 Ah1 = *reinterpret_cast<const short8*>(wb + 1 * 512 + l * 8);
      const short8 Al0 = *reinterpret_cast<const short8*>(wb + 2 * 512 + l * 8);
      const short8 Al1 = *reinterpret_cast<const short8*>(wb + 3 * 512 + l * 8);
#pragma unroll
      for (int g = 0; g < 4; ++g) {
        const int off = rowb[g] + toff;
        const short8 Bh = *reinterpret_cast<const short8*>(
            reinterpret_cast<const char*>(ph) + off);
        const short8 Bl = *reinterpret_cast<const short8*>(
            reinterpret_cast<const char*>(pl) + off);
        acc[0][g] = __builtin_amdgcn_mfma_f32_16x16x32_bf16(Ah0, Bh, acc[0][g], 0, 0, 0);
        acc[1][g] = __builtin_amdgcn_mfma_f32_16x16x32_bf16(Ah1, Bh, acc[1][g], 0, 0, 0);
        acc[0][g] = __builtin_amdgcn_mfma_f32_16x16x32_bf16(Al0, Bh, acc[0][g], 0, 0, 0);
        acc[1][g] = __builtin_amdgcn_mfma_f32_16x16x32_bf16(Al1, Bh, acc[1][g], 0, 0, 0);
        acc[0][g] = __builtin_amdgcn_mfma_f32_16x16x32_bf16(Ah0, Bl, acc[0][g], 0, 0, 0);
        acc[1][g] = __builtin_amdgcn_mfma_f32_16x16x32_bf16(Ah1, Bl, acc[1][g], 0, 0, 0);
      }
    }
  }
  // ---- epilogue: D row=(l>>4)*4+r (oc within 16), col=l&15 (px) ----
  const int gx = bx0 + x;
#pragma unroll
  for (int h = 0; h < 2; ++h)
#pragma unroll
    for (int g = 0; g < 4; ++g) {
      const int gy = by0 + 4 * wv + g;
#pragma unroll
      for (int r = 0; r < 4; ++r) {
        const int oc = h * 16 + q * 4 + r;
        out[(((b << 5) + oc) << 16) + (gy << 8) + gx] = acc[h][g][r];
      }
    }
}

// ---------------------------------------------------------------------------
// Per-(b,c) plane mean / rstd. One block per plane, no atomics.
// ---------------------------------------------------------------------------
__global__ void stats_kernel(const float* __restrict__ y,
                             float2* __restrict__ stats) {
  const int bo  = blockIdx.x;            // 0..127
  const int tid = threadIdx.x;           // 256 threads
  const float4* p = reinterpret_cast<const float4*>(y + (size_t)bo * 65536);
  float s = 0.f, q = 0.f;
  for (int i = tid; i < 16384; i += 256) {
    const float4 v = p[i];
    s += v.x + v.y + v.z + v.w;
    q += v.x * v.x + v.y * v.y + v.z * v.z + v.w * v.w;
  }
#pragma unroll
  for (int off = 32; off > 0; off >>= 1) {
    s += __shfl_down(s, off);
    q += __shfl_down(q, off);
  }
  __shared__ float sh[8];
  const int lane = tid & 63, wid = tid >> 6;
  if (lane == 0) { sh[wid] = s; sh[4 + wid] = q; }
  __syncthreads();
  if (tid == 0) {
    const float S = sh[0] + sh[1] + sh[2] + sh[3];
    const float Q = sh[4] + sh[5] + sh[6] + sh[7];
    const float mean = S * (1.f / 65536.f);
    const float var  = Q * (1.f / 65536.f) - mean * mean;
    stats[bo] = make_float2(mean, __frsqrt_rn(var + 1e-5f));
  }
}

// ---------------------------------------------------------------------------
// Final in-place InstanceNorm + LeakyReLU on d_out.
// ---------------------------------------------------------------------------
__global__ void finalize_kernel(float* __restrict__ y,
                                const float2* __restrict__ stats) {
  const int n4 = (4 * 32 * 65536) / 4;  // 2097152 float4s
  float4* p = reinterpret_cast<float4*>(y);
  for (int i = blockIdx.x * blockDim.x + threadIdx.x; i < n4;
       i += gridDim.x * blockDim.x) {
    float4 v = p[i];
    const float2 st = stats[i >> 14];   // 16384 float4 per plane
    float t;
    t = (v.x - st.x) * st.y; v.x = t < 0.f ? 0.2f * t : t;
    t = (v.y - st.x) * st.y; v.y = t < 0.f ? 0.2f * t : t;
    t = (v.z - st.x) * st.y; v.z = t < 0.f ? 0.2f * t : t;
    t = (v.w - st.x) * st.y; v.w = t < 0.f ? 0.2f * t : t;
    p[i] = v;
  }
}

// ---------------------------------------------------------------------------
extern "C" void kernel_launch(void* const* d_in, const int* in_sizes, int n_in,
                              void* d_out, int out_size, void* d_ws,
                              size_t ws_size, hipStream_t stream) {
  const float* image = (const float*)d_in[0];
  const float* w1    = (const float*)d_in[1];
  const float* w2    = (const float*)d_in[2];
  float* out = (float*)d_out;
  float* ws  = (float*)d_ws;

  // ws layout (floats): kpack1[94208] kpack2[94208] y1[8388608] stats[512]
  ushort* kern1  = (ushort*)ws;
  ushort* kern2  = (ushort*)(ws + 94208);
  float*  y1     = ws + 188416;
  float2* stats1 = (float2*)(ws + 188416 + 8388608);
  float2* stats2 = stats1 + 128;

  build_kern_kernel<<<64, 128, 0, stream>>>(w1, w2, kern1, kern2);

  dim3 cgrid(16, 16, 4);  // 16x16 px tiles, batch; 1024 blocks = 4/CU
  conv_mfma_kernel<false><<<cgrid, 256, 0, stream>>>(image, kern1, y1, nullptr);
  stats_kernel<<<128, 256, 0, stream>>>(y1, stats1);
  conv_mfma_kernel<true><<<cgrid, 256, 0, stream>>>(y1, kern2, out, stats1);
  stats_kernel<<<128, 256, 0, stream>>>(out, stats2);
  finalize_kernel<<<2048, 256, 0, stream>>>(out, stats2);
}

// Round 14
// 340.388 us; speedup vs baseline: 15.4817x; 1.1255x over previous
//
#include <hip/hip_runtime.h>

// DISCO block via bf16-split MFMA implicit GEMM.
// R12 = R9 with staging-stride bug fixed: R9 wrote ph/pl at row stride 26
// (compacted idx) while the K-loop reads at PSTR=27 -> uninitialized-LDS
// reads -> NaN. Writes now (yy*PSTR+xx)*8, matching R8's verified layout.
// R9 changes under test: (1) ds_write_b128 staging (kill 6.76M bank
// conflicts); (2) A-frag double-buffer (MfmaUtil 50 -> target 65);
// (3) stats fused into conv epilogue (removes 2x33.5MB passes).
// [R13: no-change resubmission — GPUAcquisitionTimeout, R12 unmeasured.]

typedef __attribute__((ext_vector_type(8))) short short8;
typedef __attribute__((ext_vector_type(4))) float f32x4;

#define NT      92     // 89 disk taps + 3 zero pads (multiple of 4)
#define NSTEP   23     // K-steps per ic-chunk = NT*8/32
#define PSTR    27     // LDS px row stride (26 used + 1 pad)

__device__ inline ushort f2bf(float v) {                 // RNE fp32->bf16
  uint u = __builtin_bit_cast(uint, v);
  return (ushort)((u + 0x7fffu + ((u >> 16) & 1u)) >> 16);
}
__device__ inline float bf2f(ushort h) {
  uint u = ((uint)h) << 16;
  return __builtin_bit_cast(float, u);
}

// ---------------------------------------------------------------------------
// Builder: PSI basis (fp64, matches numpy) -> dense tap weights -> hi/lo
// bf16 packed per (chunk c, kstep s, split p, ochalf h): 1KB lane-ordered
// block; lane l=(q<<4)|(oc&15) holds W[oc=16h+(l&15)][tap=4s+q][ic=8c+j].
// ---------------------------------------------------------------------------
__global__ void build_kern_kernel(const float* __restrict__ w1,
                                  const float* __restrict__ w2,
                                  ushort* __restrict__ k1,
                                  ushort* __restrict__ k2) {
  __shared__ float psi[36 * 121];
  __shared__ int tpix[NT];
  const int blk   = blockIdx.x;   // 0..63
  const int layer = blk >> 5;
  const int i     = blk & 31;     // input channel
  const int tid   = threadIdx.x;  // 128 threads
  const double PI     = 3.141592653589793;
  const double TWO_PI = 6.283185307179586;
  for (int t = tid; t < 121; t += 128) {
    const int ky = t / 11, kx = t % 11;
    const double y = (ky - 5) / 255.0;
    const double x = (kx - 5) / 255.0;
    const double r = sqrt(x * x + y * y);
    double phi = atan2(y, x);
    if (phi < 0.0) phi += TWO_PI;
    const double inside = (r <= 0.02) ? 1.0 : 0.0;
    const double dr   = 0.02 / 5.0;
    const double dphi = TWO_PI / 7.0;
    psi[t] = (float)(fmax(0.0, 1.0 - r / dr) * inside);
    for (int j = 1; j < 6; ++j) {
      const double rad = fmax(0.0, 1.0 - fabs(r - j * dr) / dr) * inside;
      for (int k = 0; k < 7; ++k) {
        double d = fmod(phi - k * dphi + PI, TWO_PI);
        if (d < 0.0) d += TWO_PI;
        d = fabs(d - PI);
        const double ang = fmax(0.0, 1.0 - d / dphi);
        psi[(1 + (j - 1) * 7 + k) * 121 + t] = (float)(rad * ang);
      }
    }
  }
  if (tid == 0) {
    int c = 0;
    for (int kdy = 0; kdy < 11; ++kdy)
      for (int kdx = 0; kdx < 11; ++kdx)
        if ((kdy - 5) * (kdy - 5) + (kdx - 5) * (kdx - 5) <= 26)
          tpix[c++] = kdy * 11 + kdx;
    for (; c < NT; ++c) tpix[c] = -1;   // zero-pad taps
  }
  __syncthreads();
  const float* w  = layer ? w2 : w1;
  ushort*      ko = layer ? k2 : k1;
  const int cch = i >> 3, j = i & 7;
  for (int idx = tid; idx < NT * 32; idx += 128) {
    const int t = idx >> 5;
    const int o = idx & 31;
    float s = 0.f;
    const int tp = tpix[t];
    if (tp >= 0) {
      const float* wp = w + (o * 32 + i) * 36;   // w[o][i][k], K=36
#pragma unroll
      for (int k = 0; k < 36; ++k) s = fmaf(wp[k], psi[k * 121 + tp], s);
    }
    const ushort hi = f2bf(s);
    const ushort lo = f2bf(s - bf2f(hi));
    const int sk = t >> 2, q = t & 3, h = o >> 4;
    const int lane = (q << 4) | (o & 15);
    const size_t b0 = ((size_t)((cch * NSTEP + sk) * 2 + 0) * 2 + h) * 512 +
                      lane * 8 + j;
    const size_t b1 = ((size_t)((cch * NSTEP + sk) * 2 + 1) * 2 + h) * 512 +
                      lane * 8 + j;
    ko[b0] = hi;
    ko[b1] = lo;
  }
}

// ---------------------------------------------------------------------------
// MFMA conv. Block: 16x16 px, 32 oc, one batch; 256 thr = 4 waves, wave =
// 4 px-rows x 32 oc. Per k-step: 4 global A-frags (double-buffered across
// steps), 8 LDS B-frags, 24 MFMAs. Epilogue: per-oc (sum,sumsq) partials
// -> LDS -> 64 global atomicAdds per block (InstanceNorm stats).
// ---------------------------------------------------------------------------
#define LOADW(W, S) do {                                                   \
    const ushort* wb_ = wc + (size_t)(S) * 2048;                           \
    W[0] = *reinterpret_cast<const short8*>(wb_ + 0 * 512 + l * 8);        \
    W[1] = *reinterpret_cast<const short8*>(wb_ + 1 * 512 + l * 8);        \
    W[2] = *reinterpret_cast<const short8*>(wb_ + 2 * 512 + l * 8);        \
    W[3] = *reinterpret_cast<const short8*>(wb_ + 3 * 512 + l * 8);        \
  } while (0)

#define STEP(W, S) do {                                                    \
    const int toff_ = toffs[(S) * 4 + q];                                  \
    _Pragma("unroll")                                                      \
    for (int g = 0; g < 4; ++g) {                                          \
      const int off_ = rowb[g] + toff_;                                    \
      const short8 Bh_ = *reinterpret_cast<const short8*>(                 \
          reinterpret_cast<const char*>(ph) + off_);                       \
      const short8 Bl_ = *reinterpret_cast<const short8*>(                 \
          reinterpret_cast<const char*>(pl) + off_);                       \
      acc[0][g] = __builtin_amdgcn_mfma_f32_16x16x32_bf16(W[0], Bh_, acc[0][g], 0, 0, 0); \
      acc[1][g] = __builtin_amdgcn_mfma_f32_16x16x32_bf16(W[1], Bh_, acc[1][g], 0, 0, 0); \
      acc[0][g] = __builtin_amdgcn_mfma_f32_16x16x32_bf16(W[2], Bh_, acc[0][g], 0, 0, 0); \
      acc[1][g] = __builtin_amdgcn_mfma_f32_16x16x32_bf16(W[3], Bh_, acc[1][g], 0, 0, 0); \
      acc[0][g] = __builtin_amdgcn_mfma_f32_16x16x32_bf16(W[0], Bl_, acc[0][g], 0, 0, 0); \
      acc[1][g] = __builtin_amdgcn_mfma_f32_16x16x32_bf16(W[1], Bl_, acc[1][g], 0, 0, 0); \
    }                                                                      \
  } while (0)

template <bool NORM_IN>
__global__ __launch_bounds__(256, 4)
void conv_mfma_kernel(const float* __restrict__ in,
                      const ushort* __restrict__ wpack,
                      float* __restrict__ out,
                      const float2* __restrict__ stats,
                      float* __restrict__ accum) {
  __shared__ __align__(16) ushort ph[26 * PSTR * 8];
  __shared__ __align__(16) ushort pl[26 * PSTR * 8];
  __shared__ int toffs[NT];
  __shared__ float2 psum[4][32];
  const int tid = threadIdx.x;
  const int l   = tid & 63;
  const int wv  = tid >> 6;        // wave 0..3
  const int x   = l & 15;
  const int q   = l >> 4;
  const int bx0 = blockIdx.x * 16;
  const int by0 = blockIdx.y * 16;
  const int b   = blockIdx.z;

  if (tid == 0) {
    int c = 0;
    for (int kdy = 0; kdy < 11; ++kdy)
      for (int kdx = 0; kdx < 11; ++kdx)
        if ((kdy - 5) * (kdy - 5) + (kdx - 5) * (kdx - 5) <= 26)
          toffs[c++] = ((kdy - 5) * PSTR + (kdx - 5)) * 16;
    for (; c < NT; ++c) toffs[c] = 0;
  }

  f32x4 acc[2][4];
#pragma unroll
  for (int h = 0; h < 2; ++h)
#pragma unroll
    for (int g = 0; g < 4; ++g) {
      acc[h][g][0] = 0.f; acc[h][g][1] = 0.f;
      acc[h][g][2] = 0.f; acc[h][g][3] = 0.f;
    }

  int rowb[4];
#pragma unroll
  for (int g = 0; g < 4; ++g)
    rowb[g] = (((4 * wv + g + 5) * PSTR + 5) + x) * 16;  // byte offset

  for (int c = 0; c < 4; ++c) {
    __syncthreads();
    // ---- stage 8 channels: fp32 -> hi/lo bf16, [y][x][8ic], b128 writes
    //      at PADDED stride PSTR (must match rowb/toffs read layout!) ----
    for (int idx = tid; idx < 26 * 26; idx += 256) {
      const int yy = idx / 26;
      const int xx = idx - yy * 26;
      const int gy = by0 + yy - 5;
      const int gx = bx0 + xx - 5;
      short8 h8 = {0, 0, 0, 0, 0, 0, 0, 0};
      short8 l8 = {0, 0, 0, 0, 0, 0, 0, 0};
      if ((unsigned)gy < 256u && (unsigned)gx < 256u) {
        const float* ip = in + (((b << 5) + (c << 3)) << 16) + (gy << 8) + gx;
#pragma unroll
        for (int ci = 0; ci < 8; ++ci) {
          float v = ip[ci << 16];
          if (NORM_IN) {
            const float2 st = stats[(b << 5) + (c << 3) + ci];
            v = (v - st.x) * st.y;
            v = v < 0.f ? 0.2f * v : v;
          }
          const ushort hi = f2bf(v);
          const ushort lo = f2bf(v - bf2f(hi));
          h8[ci] = (short)hi;
          l8[ci] = (short)lo;
        }
      }
      const int lidx = (yy * PSTR + xx) * 8;   // stride-27 layout
      *reinterpret_cast<short8*>(&ph[lidx]) = h8;
      *reinterpret_cast<short8*>(&pl[lidx]) = l8;
    }
    __syncthreads();
    // ---- K-loop: 23 k-steps of K=32, A double-buffered ----
    const ushort* wc = wpack + (size_t)c * (NSTEP * 4 * 512);
    short8 Wa[4], Wb[4];
    LOADW(Wa, 0);
    int s = 0;
    for (; s + 1 < NSTEP; s += 2) {
      LOADW(Wb, s + 1);
      STEP(Wa, s);
      if (s + 2 < NSTEP) LOADW(Wa, s + 2);
      STEP(Wb, s + 1);
    }
    STEP(Wa, NSTEP - 1);
  }
  // ---- write raw conv output: D row=(l>>4)*4+r (oc in 16), col=l&15 (px) ----
  const int gx = bx0 + x;
#pragma unroll
  for (int h = 0; h < 2; ++h)
#pragma unroll
    for (int g = 0; g < 4; ++g) {
      const int gy = by0 + 4 * wv + g;
#pragma unroll
      for (int r = 0; r < 4; ++r) {
        const int oc = h * 16 + q * 4 + r;
        out[(((b << 5) + oc) << 16) + (gy << 8) + gx] = acc[h][g][r];
      }
    }
  // ---- fused InstanceNorm partials: reduce over px, atomicAdd per (b,oc) ----
#pragma unroll
  for (int h = 0; h < 2; ++h)
#pragma unroll
    for (int r = 0; r < 4; ++r) {
      float s = 0.f, qq = 0.f;
#pragma unroll
      for (int g = 0; g < 4; ++g) {
        const float v = acc[h][g][r];
        s += v; qq += v * v;
      }
#pragma unroll
      for (int m = 1; m < 16; m <<= 1) {
        s  += __shfl_xor(s, m, 64);
        qq += __shfl_xor(qq, m, 64);
      }
      if (x == 0) psum[wv][h * 16 + q * 4 + r] = make_float2(s, qq);
    }
  __syncthreads();
  if (tid < 32) {
    const float2 a0 = psum[0][tid], a1 = psum[1][tid];
    const float2 a2 = psum[2][tid], a3 = psum[3][tid];
    atomicAdd(&accum[(b * 32 + tid) * 2 + 0], a0.x + a1.x + a2.x + a3.x);
    atomicAdd(&accum[(b * 32 + tid) * 2 + 1], a0.y + a1.y + a2.y + a3.y);
  }
}

// ---------------------------------------------------------------------------
__global__ void zero_kernel(float* __restrict__ accum) {
  if (threadIdx.x < 512) accum[threadIdx.x] = 0.f;
}

// accum (sum,sumsq) per (b,oc) -> stats (mean, rstd)
__global__ void statsfix_kernel(const float* __restrict__ accum,
                                float2* __restrict__ stats) {
  const int bo = threadIdx.x;  // 0..127
  if (bo < 128) {
    const float mean = accum[bo * 2 + 0] * (1.f / 65536.f);
    const float var  = accum[bo * 2 + 1] * (1.f / 65536.f) - mean * mean;
    stats[bo] = make_float2(mean, __frsqrt_rn(var + 1e-5f));
  }
}

// ---------------------------------------------------------------------------
// Final in-place InstanceNorm + LeakyReLU on d_out.
// ---------------------------------------------------------------------------
__global__ void finalize_kernel(float* __restrict__ y,
                                const float2* __restrict__ stats) {
  const int n4 = (4 * 32 * 65536) / 4;  // 2097152 float4s
  float4* p = reinterpret_cast<float4*>(y);
  for (int i = blockIdx.x * blockDim.x + threadIdx.x; i < n4;
       i += gridDim.x * blockDim.x) {
    float4 v = p[i];
    const float2 st = stats[i >> 14];   // 16384 float4 per plane
    float t;
    t = (v.x - st.x) * st.y; v.x = t < 0.f ? 0.2f * t : t;
    t = (v.y - st.x) * st.y; v.y = t < 0.f ? 0.2f * t : t;
    t = (v.z - st.x) * st.y; v.z = t < 0.f ? 0.2f * t : t;
    t = (v.w - st.x) * st.y; v.w = t < 0.f ? 0.2f * t : t;
    p[i] = v;
  }
}

// ---------------------------------------------------------------------------
extern "C" void kernel_launch(void* const* d_in, const int* in_sizes, int n_in,
                              void* d_out, int out_size, void* d_ws,
                              size_t ws_size, hipStream_t stream) {
  const float* image = (const float*)d_in[0];
  const float* w1    = (const float*)d_in[1];
  const float* w2    = (const float*)d_in[2];
  float* out = (float*)d_out;
  float* ws  = (float*)d_ws;

  // ws (floats): kpack1[94208] kpack2[94208] y1[8388608] accum[512] stats[512]
  ushort* kern1  = (ushort*)ws;
  ushort* kern2  = (ushort*)(ws + 94208);
  float*  y1     = ws + 188416;
  float*  accum1 = ws + 188416 + 8388608;
  float*  accum2 = accum1 + 256;
  float2* stats1 = (float2*)(accum1 + 512);
  float2* stats2 = stats1 + 128;

  build_kern_kernel<<<64, 128, 0, stream>>>(w1, w2, kern1, kern2);
  zero_kernel<<<1, 512, 0, stream>>>(accum1);   // zeroes accum1+accum2

  dim3 cgrid(16, 16, 4);  // 16x16 px tiles, batch; 1024 blocks = 4/CU
  conv_mfma_kernel<false><<<cgrid, 256, 0, stream>>>(image, kern1, y1,
                                                     nullptr, accum1);
  statsfix_kernel<<<1, 128, 0, stream>>>(accum1, stats1);
  conv_mfma_kernel<true><<<cgrid, 256, 0, stream>>>(y1, kern2, out,
                                                    stats1, accum2);
  statsfix_kernel<<<1, 128, 0, stream>>>(accum2, stats2);
  finalize_kernel<<<2048, 256, 0, stream>>>(out, stats2);
}